// Round 6
// baseline (391.664 us; speedup 1.0000x reference)
//
#include <hip/hip_runtime.h>
#include <hip/hip_bf16.h>

#define NNODES 100000
#define NEDGES 1600000
#define DIN 128
#define DOUT 128
#define NHEADS 4
#define NEG_SLOPE 0.2f
#define LN_EPS 1e-5f

typedef __attribute__((ext_vector_type(8))) short bf16x8;
typedef __attribute__((ext_vector_type(4))) float f32x4;

__device__ inline ushort f2b(float f) {
  union { float f; uint u; } v; v.f = f;
  uint r = v.u + 0x7fff + ((v.u >> 16) & 1);   // RNE
  return (ushort)(r >> 16);
}

#define NBH ((NEDGES + 255) / 256)   // 6250 hist blocks
#define NB  ((NNODES + 255) / 256)   // 391 node blocks
#define CSRCAP (NEDGES + 8 * NNODES) // padded CSR capacity (2.4M)

// ---------------- hist (+int rank) fused with W transpose+cast ----------------
__global__ __launch_bounds__(256) void k_hist_wt(
    const int* __restrict__ ei, int* __restrict__ deg, int* __restrict__ rank,
    const float* __restrict__ W, ushort* __restrict__ Wt) {
  if (blockIdx.x == NBH) {
    int t = threadIdx.x;
    int n = t >> 1;
    int kb = (t & 1) * 64;
    for (int i = 0; i < 16; ++i) {
      ushort4 p;
      p.x = f2b(W[(kb + 4 * i + 0) * DOUT + n]);
      p.y = f2b(W[(kb + 4 * i + 1) * DOUT + n]);
      p.z = f2b(W[(kb + 4 * i + 2) * DOUT + n]);
      p.w = f2b(W[(kb + 4 * i + 3) * DOUT + n]);
      *(ushort4*)&Wt[n * DIN + kb + 4 * i] = p;
    }
    return;
  }
  int e = blockIdx.x * 256 + threadIdx.x;
  if (e < NEDGES) rank[e] = atomicAdd(&deg[ei[NEDGES + e]], 1);
}

// ---------------- MFMA GEMM: direct-from-global A frags, W^T-only LDS ----------------
#define BM 128
#define LDP 136

__global__ __launch_bounds__(256) void k_gemm(
    const float* __restrict__ x, const ushort* __restrict__ Wt,
    const float* __restrict__ att_src, const float* __restrict__ att_dst,
    ushort* __restrict__ h, float* __restrict__ a_src, float* __restrict__ a_dst) {
  __shared__ __align__(16) ushort Ws[DOUT][LDP];
  const int t = threadIdx.x;
  const int brow = blockIdx.x * BM;
  {
    const int row = t >> 1, cb = (t & 1) * 64;
    const ushort* srcp = &Wt[row * DIN + cb];
#pragma unroll
    for (int i = 0; i < 8; ++i)
      *(bf16x8*)&Ws[row][cb + 8 * i] = *(const bf16x8*)(srcp + 8 * i);
  }
  __syncthreads();

  const int w = t >> 6, l = t & 63;
  const int lr = l & 15, lg = l >> 4;
  const int r0 = brow + w * 32 + lr;
  const int r1 = r0 + 16;
  const float* x0 = &x[(size_t)min(r0, NNODES - 1) * DIN + lg * 8];
  const float* x1 = &x[(size_t)min(r1, NNODES - 1) * DIN + lg * 8];

  float4 xf[2][4][2];
#pragma unroll
  for (int k0 = 0; k0 < 4; ++k0) {
    xf[0][k0][0] = *(const float4*)(x0 + k0 * 32);
    xf[0][k0][1] = *(const float4*)(x0 + k0 * 32 + 4);
    xf[1][k0][0] = *(const float4*)(x1 + k0 * 32);
    xf[1][k0][1] = *(const float4*)(x1 + k0 * 32 + 4);
  }
  bf16x8 afr[2][4];
#pragma unroll
  for (int mi = 0; mi < 2; ++mi)
#pragma unroll
    for (int k0 = 0; k0 < 4; ++k0) {
      float4 a = xf[mi][k0][0], b = xf[mi][k0][1];
      bf16x8 v;
      v[0] = (short)f2b(a.x); v[1] = (short)f2b(a.y);
      v[2] = (short)f2b(a.z); v[3] = (short)f2b(a.w);
      v[4] = (short)f2b(b.x); v[5] = (short)f2b(b.y);
      v[6] = (short)f2b(b.z); v[7] = (short)f2b(b.w);
      afr[mi][k0] = v;
    }

  f32x4 acc[2][8];
#pragma unroll
  for (int mi = 0; mi < 2; ++mi)
#pragma unroll
    for (int ni = 0; ni < 8; ++ni)
      acc[mi][ni] = (f32x4){0.f, 0.f, 0.f, 0.f};

#pragma unroll
  for (int k0 = 0; k0 < 4; ++k0) {
#pragma unroll
    for (int ni = 0; ni < 8; ++ni) {
      bf16x8 b = *(const bf16x8*)&Ws[ni * 16 + lr][k0 * 32 + lg * 8];
      acc[0][ni] = __builtin_amdgcn_mfma_f32_16x16x32_bf16(afr[0][k0], b, acc[0][ni], 0, 0, 0);
      acc[1][ni] = __builtin_amdgcn_mfma_f32_16x16x32_bf16(afr[1][k0], b, acc[1][ni], 0, 0, 0);
    }
  }

  float asr[8], adr[8];
#pragma unroll
  for (int ni = 0; ni < 8; ++ni) {
    asr[ni] = att_src[ni * 16 + lr];
    adr[ni] = att_dst[ni * 16 + lr];
  }

#pragma unroll
  for (int mi = 0; mi < 2; ++mi) {
#pragma unroll
    for (int r = 0; r < 4; ++r) {
      const int row = brow + w * 32 + mi * 16 + lg * 4 + r;
      float ps[NHEADS] = {0.f, 0.f, 0.f, 0.f};
      float pd[NHEADS] = {0.f, 0.f, 0.f, 0.f};
#pragma unroll
      for (int ni = 0; ni < 8; ++ni) {
        float v = acc[mi][ni][r];
        ps[ni >> 1] += v * asr[ni];
        pd[ni >> 1] += v * adr[ni];
        if (row < NNODES) h[(size_t)row * DOUT + ni * 16 + lr] = f2b(v);
      }
#pragma unroll
      for (int off = 1; off < 16; off <<= 1) {
#pragma unroll
        for (int hh = 0; hh < NHEADS; ++hh) {
          ps[hh] += __shfl_xor(ps[hh], off);
          pd[hh] += __shfl_xor(pd[hh], off);
        }
      }
      if (lr == 0 && row < NNODES) {
        *(float4*)&a_src[row * NHEADS] = make_float4(ps[0], ps[1], ps[2], ps[3]);
        *(float4*)&a_dst[row * NHEADS] = make_float4(pd[0], pd[1], pd[2], pd[3]);
      }
    }
  }
}

// ---------------- per-block sums of PADDED degree ----------------
__global__ __launch_bounds__(256) void k_blocksum(const int* __restrict__ deg,
                                                  int* __restrict__ bsum) {
  int i = blockIdx.x * 256 + threadIdx.x;
  int d = (i < NNODES) ? deg[i] : 0;
  int dp = (d + 7) & ~7;
  for (int off = 1; off < 64; off <<= 1) dp += __shfl_xor(dp, off);
  __shared__ int s[4];
  if ((threadIdx.x & 63) == 0) s[threadIdx.x >> 6] = dp;
  __syncthreads();
  if (threadIdx.x == 0) bsum[blockIdx.x] = s[0] + s[1] + s[2] + s[3];
}

// ---------------- padded offsets (inline block-prefix) + gap fill ----------------
__global__ __launch_bounds__(256) void k_offsets(
    const int* __restrict__ deg, const int* __restrict__ bsum,
    int* __restrict__ offs, int* __restrict__ ssrc, float4* __restrict__ ps) {
  const int t = threadIdx.x;
  const int bid = blockIdx.x;
  const int i = bid * 256 + t;
  // prefix over previous blocks' sums
  int pacc = 0;
  for (int j = t; j < bid; j += 256) pacc += bsum[j];
  for (int off = 1; off < 64; off <<= 1) pacc += __shfl_xor(pacc, off);
  __shared__ int wsum[4];
  if ((t & 63) == 0) wsum[t >> 6] = pacc;
  __syncthreads();
  const int pre = wsum[0] + wsum[1] + wsum[2] + wsum[3];

  const int d = (i < NNODES) ? deg[i] : 0;
  const int dp = (d + 7) & ~7;
  __shared__ int s[256];
  s[t] = dp;
  __syncthreads();
  for (int off = 1; off < 256; off <<= 1) {
    int a = 0;
    if (t >= off) a = s[t - off];
    __syncthreads();
    s[t] += a;
    __syncthreads();
  }
  const int excl = s[t] - dp + pre;
  if (i < NNODES) {
    offs[i] = excl;
    // fill padding gap: zero-prob, src 0
    for (int g = d; g < dp; ++g) {
      ssrc[excl + g] = 0;
      ps[excl + g] = make_float4(0.f, 0.f, 0.f, 0.f);
    }
    if (i == NNODES - 1) offs[NNODES] = excl + dp;
  }
}

// ---------------- scatter + per-edge softmax numerator (exp moved here) ----------
__global__ void k_scatter_p(const int* __restrict__ ei, const int* __restrict__ rank,
                            const int* __restrict__ offs, const float* __restrict__ a_src,
                            const float* __restrict__ a_dst, int* __restrict__ ssrc,
                            float4* __restrict__ ps) {
  int e = blockIdx.x * blockDim.x + threadIdx.x;
  if (e >= NEDGES) return;
  int src = ei[e];
  int dst = ei[NEDGES + e];
  int pos = offs[dst] + rank[e];
  float4 as = *(const float4*)&a_src[(size_t)src * NHEADS];
  float4 ad = *(const float4*)&a_dst[(size_t)dst * NHEADS];
  float e0 = as.x + ad.x, e1 = as.y + ad.y, e2 = as.z + ad.z, e3 = as.w + ad.w;
  e0 = fmaxf(e0, NEG_SLOPE * e0); e1 = fmaxf(e1, NEG_SLOPE * e1);
  e2 = fmaxf(e2, NEG_SLOPE * e2); e3 = fmaxf(e3, NEG_SLOPE * e3);
  float4 p = make_float4(__expf(e0), __expf(e1), __expf(e2), __expf(e3));
  ssrc[pos] = src;
  ps[pos] = p;
}

// ---------------- fused aggregate + bias + LN + PReLU + residual ----------------
// One 64-lane wave per node; lane l owns channels 2l,2l+1 (head = l>>4).
// Edge groups padded to x8 with p=0 -> no tail loop, no masking.
__global__ __launch_bounds__(256) void k_agg(
    const int* __restrict__ offs, const int* __restrict__ ssrc,
    const float* __restrict__ ps, const ushort* __restrict__ h,
    const float* __restrict__ x, const float* __restrict__ bias,
    const float* __restrict__ gamma, const float* __restrict__ beta,
    const float* __restrict__ prelu, float* __restrict__ out) {
  const int n = blockIdx.x * 4 + (threadIdx.x >> 6);
  const int l = threadIdx.x & 63;
  const int head = l >> 4;
  const int beg = offs[n], end = offs[n + 1];
  const uint* hb = (const uint*)h;
  float acc0 = 0.f, acc1 = 0.f, ssum = 0.f;

  for (int i = beg; i < end; i += 8) {
    const int s0 = ssrc[i + 0], s1 = ssrc[i + 1], s2 = ssrc[i + 2], s3 = ssrc[i + 3];
    const int s4 = ssrc[i + 4], s5 = ssrc[i + 5], s6 = ssrc[i + 6], s7 = ssrc[i + 7];
    const float p0 = ps[4 * (i + 0) + head];
    const float p1 = ps[4 * (i + 1) + head];
    const float p2 = ps[4 * (i + 2) + head];
    const float p3 = ps[4 * (i + 3) + head];
    const float p4 = ps[4 * (i + 4) + head];
    const float p5 = ps[4 * (i + 5) + head];
    const float p6 = ps[4 * (i + 6) + head];
    const float p7 = ps[4 * (i + 7) + head];
    const uint h0 = hb[(((uint)s0) << 6) + l];
    const uint h1 = hb[(((uint)s1) << 6) + l];
    const uint h2 = hb[(((uint)s2) << 6) + l];
    const uint h3 = hb[(((uint)s3) << 6) + l];
    const uint h4 = hb[(((uint)s4) << 6) + l];
    const uint h5 = hb[(((uint)s5) << 6) + l];
    const uint h6 = hb[(((uint)s6) << 6) + l];
    const uint h7 = hb[(((uint)s7) << 6) + l];
    ssum += ((p0 + p1) + (p2 + p3)) + ((p4 + p5) + (p6 + p7));
    acc0 += p0 * __uint_as_float(h0 << 16) + p1 * __uint_as_float(h1 << 16) +
            p2 * __uint_as_float(h2 << 16) + p3 * __uint_as_float(h3 << 16) +
            p4 * __uint_as_float(h4 << 16) + p5 * __uint_as_float(h5 << 16) +
            p6 * __uint_as_float(h6 << 16) + p7 * __uint_as_float(h7 << 16);
    acc1 += p0 * __uint_as_float(h0 & 0xffff0000u) + p1 * __uint_as_float(h1 & 0xffff0000u) +
            p2 * __uint_as_float(h2 & 0xffff0000u) + p3 * __uint_as_float(h3 & 0xffff0000u) +
            p4 * __uint_as_float(h4 & 0xffff0000u) + p5 * __uint_as_float(h5 & 0xffff0000u) +
            p6 * __uint_as_float(h6 & 0xffff0000u) + p7 * __uint_as_float(h7 & 0xffff0000u);
  }

  float inv = 1.f / (ssum + 1e-16f);
  float v0 = acc0 * inv + bias[2 * l];
  float v1 = acc1 * inv + bias[2 * l + 1];
  float s1 = v0 + v1, s2 = v0 * v0 + v1 * v1;
  for (int off = 1; off < 64; off <<= 1) {
    s1 += __shfl_xor(s1, off);
    s2 += __shfl_xor(s2, off);
  }
  float mu = s1 * (1.f / DOUT);
  float var = s2 * (1.f / DOUT) - mu * mu;
  float rs = rsqrtf(var + LN_EPS);
  float pw = prelu[0];
  float2 xr = *(const float2*)&x[(size_t)n * DIN + 2 * l];
  float o0 = (v0 - mu) * rs * gamma[2 * l] + beta[2 * l];
  o0 = (o0 >= 0.f) ? o0 : pw * o0;
  float o1 = (v1 - mu) * rs * gamma[2 * l + 1] + beta[2 * l + 1];
  o1 = (o1 >= 0.f) ? o1 : pw * o1;
  *(float2*)&out[(size_t)n * DOUT + 2 * l] = make_float2(o0 + xr.x, o1 + xr.y);
}

// ---------------- launch ----------------
extern "C" void kernel_launch(void* const* d_in, const int* in_sizes, int n_in,
                              void* d_out, int out_size, void* d_ws, size_t ws_size,
                              hipStream_t stream) {
  const float* x       = (const float*)d_in[0];
  const int*   ei      = (const int*)d_in[1];
  const float* W       = (const float*)d_in[2];
  const float* att_src = (const float*)d_in[3];
  const float* att_dst = (const float*)d_in[4];
  const float* bias    = (const float*)d_in[5];
  const float* gamma   = (const float*)d_in[6];
  const float* beta    = (const float*)d_in[7];
  const float* prelu   = (const float*)d_in[8];
  float* out = (float*)d_out;

  char* ws = (char*)d_ws;
  size_t off = 0;
  auto alloc = [&](size_t bytes) -> void* {
    void* p = ws + off;
    off += (bytes + 255) & ~(size_t)255;
    return p;
  };
  ushort* h     = (ushort*)alloc((size_t)NNODES * DOUT * 2);
  ushort* Wt    = (ushort*)alloc((size_t)DIN * DOUT * 2);
  float* a_src  = (float*)alloc((size_t)NNODES * NHEADS * 4);
  float* a_dst  = (float*)alloc((size_t)NNODES * NHEADS * 4);
  int*   deg    = (int*)alloc((size_t)NNODES * 4);
  int*   offs   = (int*)alloc((size_t)(NNODES + 1) * 4);
  int*   rank   = (int*)alloc((size_t)NEDGES * 4);
  int*   ssrc   = (int*)alloc((size_t)CSRCAP * 4);
  float4* ps    = (float4*)alloc((size_t)CSRCAP * 16);
  int*   bsum   = (int*)alloc((size_t)NB * 4);

  hipMemsetAsync(deg, 0, (size_t)NNODES * 4, stream);
  k_hist_wt<<<NBH + 1, 256, 0, stream>>>(ei, deg, rank, W, Wt);
  k_gemm<<<(NNODES + BM - 1) / BM, 256, 0, stream>>>(x, Wt, att_src, att_dst, h,
                                                     a_src, a_dst);
  k_blocksum<<<NB, 256, 0, stream>>>(deg, bsum);
  k_offsets<<<NB, 256, 0, stream>>>(deg, bsum, offs, ssrc, ps);
  k_scatter_p<<<NBH, 256, 0, stream>>>(ei, rank, offs, a_src, a_dst, ssrc, ps);
  k_agg<<<NNODES / 4, 256, 0, stream>>>(offs, ssrc, (const float*)ps, h, x, bias,
                                        gamma, beta, prelu, out);
}

// Round 11
// 367.052 us; speedup vs baseline: 1.0671x; 1.0671x over previous
//
#include <hip/hip_runtime.h>
#include <hip/hip_bf16.h>
#include <hip/hip_fp16.h>

#define NNODES 100000
#define NEDGES 1600000
#define DIN 128
#define DOUT 128
#define NHEADS 4
#define NEG_SLOPE 0.2f
#define LN_EPS 1e-5f

typedef __attribute__((ext_vector_type(8))) short bf16x8;
typedef __attribute__((ext_vector_type(4))) float f32x4;

__device__ inline ushort f2b(float f) {
  union { float f; uint u; } v; v.f = f;
  uint r = v.u + 0x7fff + ((v.u >> 16) & 1);   // RNE
  return (ushort)(r >> 16);
}
__device__ inline uint packh2(float a, float b) {
  __half ha = __float2half_rn(a), hb = __float2half_rn(b);
  union { __half h; ushort u; } ua, ub; ua.h = ha; ub.h = hb;
  return (uint)ua.u | ((uint)ub.u << 16);
}
__device__ inline float exth(uint w, int hi) {
  union { ushort u; __half h; } v;
  v.u = hi ? (ushort)(w >> 16) : (ushort)(w & 0xffffu);
  return __half2float(v.h);
}

#define NB4 ((NEDGES + 1023) / 1024)  // 1563 quad-edge blocks
#define NB  ((NNODES + 255) / 256)    // 391 node blocks
#define CSRCAP (NEDGES + 8 * NNODES)  // padded CSR capacity (2.4M)

// ---------------- hist x4 (+int rank) fused with W transpose+cast ----------------
__global__ __launch_bounds__(256) void k_hist_wt(
    const int* __restrict__ ei, int* __restrict__ deg, int* __restrict__ rank,
    const float* __restrict__ W, ushort* __restrict__ Wt) {
  if (blockIdx.x == NB4) {
    int t = threadIdx.x;
    int n = t >> 1;
    int kb = (t & 1) * 64;
    for (int i = 0; i < 16; ++i) {
      ushort4 p;
      p.x = f2b(W[(kb + 4 * i + 0) * DOUT + n]);
      p.y = f2b(W[(kb + 4 * i + 1) * DOUT + n]);
      p.z = f2b(W[(kb + 4 * i + 2) * DOUT + n]);
      p.w = f2b(W[(kb + 4 * i + 3) * DOUT + n]);
      *(ushort4*)&Wt[n * DIN + kb + 4 * i] = p;
    }
    return;
  }
  const int base = blockIdx.x * 1024 + threadIdx.x;
  if (base + 768 < NEDGES) {
    const int d0 = min(ei[NEDGES + base + 0], NNODES - 1);
    const int d1 = min(ei[NEDGES + base + 256], NNODES - 1);
    const int d2 = min(ei[NEDGES + base + 512], NNODES - 1);
    const int d3 = min(ei[NEDGES + base + 768], NNODES - 1);
    rank[base + 0]   = atomicAdd(&deg[d0], 1);
    rank[base + 256] = atomicAdd(&deg[d1], 1);
    rank[base + 512] = atomicAdd(&deg[d2], 1);
    rank[base + 768] = atomicAdd(&deg[d3], 1);
  } else {
    for (int k = 0; k < 4; ++k) {
      int e = base + k * 256;
      if (e < NEDGES) rank[e] = atomicAdd(&deg[min(ei[NEDGES + e], NNODES - 1)], 1);
    }
  }
}

// ---------------- MFMA GEMM: direct-from-global A frags, W^T-only LDS ----------------
#define BM 128
#define LDP 136

__global__ __launch_bounds__(256) void k_gemm(
    const float* __restrict__ x, const ushort* __restrict__ Wt,
    const float* __restrict__ att_src, const float* __restrict__ att_dst,
    ushort* __restrict__ h, float* __restrict__ a_src, float* __restrict__ a_dst) {
  __shared__ __align__(16) ushort Ws[DOUT][LDP];
  const int t = threadIdx.x;
  const int brow = blockIdx.x * BM;
  {
    const int row = t >> 1, cb = (t & 1) * 64;
    const ushort* srcp = &Wt[row * DIN + cb];
#pragma unroll
    for (int i = 0; i < 8; ++i)
      *(bf16x8*)&Ws[row][cb + 8 * i] = *(const bf16x8*)(srcp + 8 * i);
  }
  __syncthreads();

  const int w = t >> 6, l = t & 63;
  const int lr = l & 15, lg = l >> 4;
  const int r0 = brow + w * 32 + lr;
  const int r1 = r0 + 16;
  const float* x0 = &x[(size_t)min(r0, NNODES - 1) * DIN + lg * 8];
  const float* x1 = &x[(size_t)min(r1, NNODES - 1) * DIN + lg * 8];

  float4 xf[2][4][2];
#pragma unroll
  for (int k0 = 0; k0 < 4; ++k0) {
    xf[0][k0][0] = *(const float4*)(x0 + k0 * 32);
    xf[0][k0][1] = *(const float4*)(x0 + k0 * 32 + 4);
    xf[1][k0][0] = *(const float4*)(x1 + k0 * 32);
    xf[1][k0][1] = *(const float4*)(x1 + k0 * 32 + 4);
  }
  bf16x8 afr[2][4];
#pragma unroll
  for (int mi = 0; mi < 2; ++mi)
#pragma unroll
    for (int k0 = 0; k0 < 4; ++k0) {
      float4 a = xf[mi][k0][0], b = xf[mi][k0][1];
      bf16x8 v;
      v[0] = (short)f2b(a.x); v[1] = (short)f2b(a.y);
      v[2] = (short)f2b(a.z); v[3] = (short)f2b(a.w);
      v[4] = (short)f2b(b.x); v[5] = (short)f2b(b.y);
      v[6] = (short)f2b(b.z); v[7] = (short)f2b(b.w);
      afr[mi][k0] = v;
    }

  f32x4 acc[2][8];
#pragma unroll
  for (int mi = 0; mi < 2; ++mi)
#pragma unroll
    for (int ni = 0; ni < 8; ++ni)
      acc[mi][ni] = (f32x4){0.f, 0.f, 0.f, 0.f};

#pragma unroll
  for (int k0 = 0; k0 < 4; ++k0) {
#pragma unroll
    for (int ni = 0; ni < 8; ++ni) {
      bf16x8 b = *(const bf16x8*)&Ws[ni * 16 + lr][k0 * 32 + lg * 8];
      acc[0][ni] = __builtin_amdgcn_mfma_f32_16x16x32_bf16(afr[0][k0], b, acc[0][ni], 0, 0, 0);
      acc[1][ni] = __builtin_amdgcn_mfma_f32_16x16x32_bf16(afr[1][k0], b, acc[1][ni], 0, 0, 0);
    }
  }

  float asr[8], adr[8];
#pragma unroll
  for (int ni = 0; ni < 8; ++ni) {
    asr[ni] = att_src[ni * 16 + lr];
    adr[ni] = att_dst[ni * 16 + lr];
  }

#pragma unroll
  for (int mi = 0; mi < 2; ++mi) {
#pragma unroll
    for (int r = 0; r < 4; ++r) {
      const int row = brow + w * 32 + mi * 16 + lg * 4 + r;
      float ps[NHEADS] = {0.f, 0.f, 0.f, 0.f};
      float pd[NHEADS] = {0.f, 0.f, 0.f, 0.f};
#pragma unroll
      for (int ni = 0; ni < 8; ++ni) {
        float v = acc[mi][ni][r];
        ps[ni >> 1] += v * asr[ni];
        pd[ni >> 1] += v * adr[ni];
        if (row < NNODES) h[(size_t)row * DOUT + ni * 16 + lr] = f2b(v);
      }
#pragma unroll
      for (int off = 1; off < 16; off <<= 1) {
#pragma unroll
        for (int hh = 0; hh < NHEADS; ++hh) {
          ps[hh] += __shfl_xor(ps[hh], off);
          pd[hh] += __shfl_xor(pd[hh], off);
        }
      }
      if (lr == 0 && row < NNODES) {
        *(float4*)&a_src[row * NHEADS] = make_float4(ps[0], ps[1], ps[2], ps[3]);
        *(float4*)&a_dst[row * NHEADS] = make_float4(pd[0], pd[1], pd[2], pd[3]);
      }
    }
  }
}

// ---------------- per-block sums of PADDED degree ----------------
__global__ __launch_bounds__(256) void k_blocksum(const int* __restrict__ deg,
                                                  int* __restrict__ bsum) {
  int i = blockIdx.x * 256 + threadIdx.x;
  int d = (i < NNODES) ? deg[i] : 0;
  int dp = (d + 7) & ~7;
  for (int off = 1; off < 64; off <<= 1) dp += __shfl_xor(dp, off);
  __shared__ int s[4];
  if ((threadIdx.x & 63) == 0) s[threadIdx.x >> 6] = dp;
  __syncthreads();
  if (threadIdx.x == 0) bsum[blockIdx.x] = s[0] + s[1] + s[2] + s[3];
}

// ---------------- padded offsets (inline block-prefix) + gap fill ----------------
__global__ __launch_bounds__(256) void k_offsets(
    const int* __restrict__ deg, const int* __restrict__ bsum,
    int* __restrict__ offs, int4* __restrict__ meta) {
  const int t = threadIdx.x;
  const int bid = blockIdx.x;
  const int i = bid * 256 + t;
  int pacc = 0;
  for (int j = t; j < bid; j += 256) pacc += bsum[j];
  for (int off = 1; off < 64; off <<= 1) pacc += __shfl_xor(pacc, off);
  __shared__ int wsum[4];
  if ((t & 63) == 0) wsum[t >> 6] = pacc;
  __syncthreads();
  const int pre = wsum[0] + wsum[1] + wsum[2] + wsum[3];

  const int d = (i < NNODES) ? deg[i] : 0;
  const int dp = (d + 7) & ~7;
  __shared__ int s[256];
  s[t] = dp;
  __syncthreads();
  for (int off = 1; off < 256; off <<= 1) {
    int a = 0;
    if (t >= off) a = s[t - off];
    __syncthreads();
    s[t] += a;
    __syncthreads();
  }
  const int excl = s[t] - dp + pre;
  if (i < NNODES) {
    offs[i] = excl;
    const int4 z = make_int4(0, 0, 0, 0);   // p=0 (half), src=0
    for (int g = d; g < dp; ++g) {
      int gp = min(excl + g, CSRCAP - 1);
      meta[gp] = z;
    }
    if (i == NNODES - 1) offs[NNODES] = excl + dp;
  }
}

// ---------------- scatter x4: packed {src, half2(p0,p1), half2(p2,p3)} ----------
// Defensive clamps (identity on valid data): src/dst in [0,NNODES), pos < CSRCAP.
__global__ __launch_bounds__(256) void k_scatter_p(
    const int* __restrict__ ei, const int* __restrict__ rank,
    const int* __restrict__ offs, const float* __restrict__ a_src,
    const float* __restrict__ a_dst, int4* __restrict__ meta) {
  const int base = blockIdx.x * 1024 + threadIdx.x;

#define SCAT_BODY(EIDX)                                                        \
  {                                                                            \
    const int ee = (EIDX);                                                     \
    const int src = min(ei[ee], NNODES - 1);                                   \
    const int dst = min(ei[NEDGES + ee], NNODES - 1);                          \
    const int pos = min(offs[dst] + rank[ee], CSRCAP - 1);                     \
    const float4 as = *(const float4*)&a_src[(size_t)src * NHEADS];            \
    const float4 ad = *(const float4*)&a_dst[(size_t)dst * NHEADS];            \
    float e0 = as.x + ad.x, e1 = as.y + ad.y;                                  \
    float e2 = as.z + ad.z, e3 = as.w + ad.w;                                  \
    e0 = fmaxf(e0, NEG_SLOPE * e0); e1 = fmaxf(e1, NEG_SLOPE * e1);            \
    e2 = fmaxf(e2, NEG_SLOPE * e2); e3 = fmaxf(e3, NEG_SLOPE * e3);            \
    const uint w1 = packh2(__expf(e0), __expf(e1));                            \
    const uint w2 = packh2(__expf(e2), __expf(e3));                            \
    meta[pos] = make_int4(src, (int)w1, (int)w2, 0);                           \
  }

  if (base + 768 < NEDGES) {
    SCAT_BODY(base + 0)
    SCAT_BODY(base + 256)
    SCAT_BODY(base + 512)
    SCAT_BODY(base + 768)
  } else {
    for (int k = 0; k < 4; ++k) {
      const int e = base + k * 256;
      if (e < NEDGES) SCAT_BODY(e)
    }
  }
#undef SCAT_BODY
}

// ---------------- fused aggregate + bias + LN + PReLU + residual ----------------
// One 64-lane wave per node; lane l owns channels 2l,2l+1 (head = l>>4).
// Edge groups padded to x8 with p=0 -> no tail loop. Meta is one 16B line/edge.
__global__ __launch_bounds__(256) void k_agg(
    const int* __restrict__ offs, const int4* __restrict__ meta,
    const ushort* __restrict__ h, const float* __restrict__ x,
    const float* __restrict__ bias, const float* __restrict__ gamma,
    const float* __restrict__ beta, const float* __restrict__ prelu,
    float* __restrict__ out) {
  const int n = blockIdx.x * 4 + (threadIdx.x >> 6);
  const int l = threadIdx.x & 63;
  const int head = l >> 4;
  const int hsel2 = head & 2, hsel1 = head & 1;
  const int beg = offs[n], end = offs[n + 1];
  const uint* hb = (const uint*)h;
  float acc0 = 0.f, acc1 = 0.f, ssum = 0.f;

  for (int i = beg; i < end; i += 8) {
    const int4 m0 = meta[i + 0];
    const int4 m1 = meta[i + 1];
    const int4 m2 = meta[i + 2];
    const int4 m3 = meta[i + 3];
    const int4 m4 = meta[i + 4];
    const int4 m5 = meta[i + 5];
    const int4 m6 = meta[i + 6];
    const int4 m7 = meta[i + 7];
    const uint s0 = min((uint)m0.x, (uint)(NNODES - 1));
    const uint s1 = min((uint)m1.x, (uint)(NNODES - 1));
    const uint s2 = min((uint)m2.x, (uint)(NNODES - 1));
    const uint s3 = min((uint)m3.x, (uint)(NNODES - 1));
    const uint s4 = min((uint)m4.x, (uint)(NNODES - 1));
    const uint s5 = min((uint)m5.x, (uint)(NNODES - 1));
    const uint s6 = min((uint)m6.x, (uint)(NNODES - 1));
    const uint s7 = min((uint)m7.x, (uint)(NNODES - 1));
    const uint h0 = hb[(s0 << 6) + l];
    const uint h1 = hb[(s1 << 6) + l];
    const uint h2 = hb[(s2 << 6) + l];
    const uint h3 = hb[(s3 << 6) + l];
    const uint h4 = hb[(s4 << 6) + l];
    const uint h5 = hb[(s5 << 6) + l];
    const uint h6 = hb[(s6 << 6) + l];
    const uint h7 = hb[(s7 << 6) + l];
    const float p0 = exth(hsel2 ? (uint)m0.z : (uint)m0.y, hsel1);
    const float p1 = exth(hsel2 ? (uint)m1.z : (uint)m1.y, hsel1);
    const float p2 = exth(hsel2 ? (uint)m2.z : (uint)m2.y, hsel1);
    const float p3 = exth(hsel2 ? (uint)m3.z : (uint)m3.y, hsel1);
    const float p4 = exth(hsel2 ? (uint)m4.z : (uint)m4.y, hsel1);
    const float p5 = exth(hsel2 ? (uint)m5.z : (uint)m5.y, hsel1);
    const float p6 = exth(hsel2 ? (uint)m6.z : (uint)m6.y, hsel1);
    const float p7 = exth(hsel2 ? (uint)m7.z : (uint)m7.y, hsel1);
    ssum += ((p0 + p1) + (p2 + p3)) + ((p4 + p5) + (p6 + p7));
    acc0 += p0 * __uint_as_float(h0 << 16) + p1 * __uint_as_float(h1 << 16) +
            p2 * __uint_as_float(h2 << 16) + p3 * __uint_as_float(h3 << 16) +
            p4 * __uint_as_float(h4 << 16) + p5 * __uint_as_float(h5 << 16) +
            p6 * __uint_as_float(h6 << 16) + p7 * __uint_as_float(h7 << 16);
    acc1 += p0 * __uint_as_float(h0 & 0xffff0000u) + p1 * __uint_as_float(h1 & 0xffff0000u) +
            p2 * __uint_as_float(h2 & 0xffff0000u) + p3 * __uint_as_float(h3 & 0xffff0000u) +
            p4 * __uint_as_float(h4 & 0xffff0000u) + p5 * __uint_as_float(h5 & 0xffff0000u) +
            p6 * __uint_as_float(h6 & 0xffff0000u) + p7 * __uint_as_float(h7 & 0xffff0000u);
  }

  float inv = 1.f / (ssum + 1e-16f);
  float v0 = acc0 * inv + bias[2 * l];
  float v1 = acc1 * inv + bias[2 * l + 1];
  float s1 = v0 + v1, s2 = v0 * v0 + v1 * v1;
  for (int off = 1; off < 64; off <<= 1) {
    s1 += __shfl_xor(s1, off);
    s2 += __shfl_xor(s2, off);
  }
  float mu = s1 * (1.f / DOUT);
  float var = s2 * (1.f / DOUT) - mu * mu;
  float rs = rsqrtf(var + LN_EPS);
  float pw = prelu[0];
  float2 xr = *(const float2*)&x[(size_t)n * DIN + 2 * l];
  float o0 = (v0 - mu) * rs * gamma[2 * l] + beta[2 * l];
  o0 = (o0 >= 0.f) ? o0 : pw * o0;
  float o1 = (v1 - mu) * rs * gamma[2 * l + 1] + beta[2 * l + 1];
  o1 = (o1 >= 0.f) ? o1 : pw * o1;
  *(float2*)&out[(size_t)n * DOUT + 2 * l] = make_float2(o0 + xr.x, o1 + xr.y);
}

// ---------------- launch ----------------
extern "C" void kernel_launch(void* const* d_in, const int* in_sizes, int n_in,
                              void* d_out, int out_size, void* d_ws, size_t ws_size,
                              hipStream_t stream) {
  const float* x       = (const float*)d_in[0];
  const int*   ei      = (const int*)d_in[1];
  const float* W       = (const float*)d_in[2];
  const float* att_src = (const float*)d_in[3];
  const float* att_dst = (const float*)d_in[4];
  const float* bias    = (const float*)d_in[5];
  const float* gamma   = (const float*)d_in[6];
  const float* beta    = (const float*)d_in[7];
  const float* prelu   = (const float*)d_in[8];
  float* out = (float*)d_out;

  char* ws = (char*)d_ws;
  size_t off = 0;
  auto alloc = [&](size_t bytes) -> void* {
    void* p = ws + off;
    off += (bytes + 255) & ~(size_t)255;
    return p;
  };
  ushort* h     = (ushort*)alloc((size_t)NNODES * DOUT * 2);
  ushort* Wt    = (ushort*)alloc((size_t)DIN * DOUT * 2);
  float* a_src  = (float*)alloc((size_t)NNODES * NHEADS * 4);
  float* a_dst  = (float*)alloc((size_t)NNODES * NHEADS * 4);
  int*   deg    = (int*)alloc((size_t)NNODES * 4);
  int*   offs   = (int*)alloc((size_t)(NNODES + 1) * 4);
  int*   rank   = (int*)alloc((size_t)NEDGES * 4);
  int4*  meta   = (int4*)alloc((size_t)CSRCAP * 16);
  int*   bsum   = (int*)alloc((size_t)NB * 4);

  hipMemsetAsync(deg, 0, (size_t)NNODES * 4, stream);
  k_hist_wt<<<NB4 + 1, 256, 0, stream>>>(ei, deg, rank, W, Wt);
  k_gemm<<<(NNODES + BM - 1) / BM, 256, 0, stream>>>(x, Wt, att_src, att_dst, h,
                                                     a_src, a_dst);
  k_blocksum<<<NB, 256, 0, stream>>>(deg, bsum);
  k_offsets<<<NB, 256, 0, stream>>>(deg, bsum, offs, meta);
  k_scatter_p<<<NB4, 256, 0, stream>>>(ei, rank, offs, a_src, a_dst, meta);
  k_agg<<<NNODES / 4, 256, 0, stream>>>(offs, meta, h, x, bias, gamma, beta,
                                        prelu, out);
}